// Round 5
// baseline (233.116 us; speedup 1.0000x reference)
//
#include <hip/hip_runtime.h>
#include <math.h>

// Problem constants (match reference)
constexpr int B = 256;
constexpr int T = 16384;
constexpr int K = 3;

// Speculative chunking: emit after 512-step warm-up (proven R5/R6).
constexpr int CHUNK = 256;
constexpr int WARM  = 512;

// Conv tiling: 64 chains x 128 timesteps per block, 4 waves x 32 t each.
constexpr int CBT = 128;
constexpr int CWT = 32;

// R11 theory: scan is PER-WAVE in-flight limited (~7 GB/s/wave: R0/R7/R8/R10
// all pinned there with 1 wave/CU; m13 proves 24.6 GB/s/CU at high occupancy).
// Fix: 4 waves per block SHARE one group-load stream. Block (bg,c) covers
// chunk c as 4 time-staggered sub-chunks of 64 t (one per wave); all waves
// consume the SAME 12 KB group per phase from a 6-slab LDS ring; each wave
// issues 3 of the 12 global_load_lds per phase (4x block-level in-flight at
// unchanged per-wave depth). Bytes unchanged (48 groups/block); per-wave
// numerics bit-identical (every emit group behind >=512 warm steps, or exact
// from t=0 for c<=1).
//
// w32 panel layout [T/16][4 bg][12 q][64 lane] x 16B (float4):
// float4 q of lane i = stream floats (4q..4q+3) of chain (bg*64+i), stream
// ordered (t_local 0..15) x (ch 0..2). Lane-coalesced on both sides.

// ---------------------------------------------------------------------------
// Conv: causal k=8/16/32 in f64 (same tap order / fma / scale as R2-R10).
// UNCHANGED from the passing R10 kernel.
// ---------------------------------------------------------------------------
__global__ __launch_bounds__(256, 2) void conv_kernel(
    const float* __restrict__ x,
    const float* __restrict__ w0f,
    const float* __restrict__ w1f,
    const float* __restrict__ w2f,
    float*  __restrict__ u_out,   // [B][K][T] f32
    float*  __restrict__ w32)     // panel layout above
{
    const int blk = blockIdx.x;            // 512 blocks
    const int bgi = blk >> 7;              // 4 b-tiles
    const int t0  = (blk & 127) * CBT;     // 128 t-tiles
    const int b0  = bgi * 64;
    const int tid = threadIdx.x;

    __shared__ float sx[64][164];          // cols t0-32 .. t0+127, +4 pad
    for (int k = tid; k < 64 * 40; k += 256) {
        const int r  = k / 40;
        const int c4 = k - r * 40;
        const int g  = t0 - 32 + 4 * c4;
        float4 v = make_float4(0.f, 0.f, 0.f, 0.f);
        if (g >= 0) v = *(const float4*)(x + (size_t)(b0 + r) * T + g);
        *(float4*)&sx[r][4 * c4] = v;
    }
    __syncthreads();

    const int lane    = tid & 63;
    const int w       = tid >> 6;
    const int t_start = t0 + CWT * w;

    double w0d[8], w1d[16], w2d[32];
#pragma unroll
    for (int i = 0; i < 8; ++i)  w0d[i] = (double)w0f[i];
#pragma unroll
    for (int i = 0; i < 16; ++i) w1d[i] = (double)w1f[i];
#pragma unroll
    for (int i = 0; i < 32; ++i) w2d[i] = (double)w2f[i];

    // ring window: win[t & 31] = x[chain][t]
    double win[32];
#pragma unroll
    for (int k = 1; k < 32; ++k) win[k] = (double)sx[lane][CWT * w + k];

    const double s8  = 1.0 / sqrt(8.0);
    const double s32 = 1.0 / sqrt(32.0);

    float fr0[16], fr1[16], fr2[16];
    float4 pf;                              // panel float4 batcher
    float* uf = u_out + (size_t)(b0 + lane) * (3 * T);

// Put stream value v at slot D; flush the float4 when last component lands.
// Store instr: 64 lanes x 16 B contiguous = 1 KB coalesced.
#define PPUT(v, D) do {                                                       \
    const float _pv = (v);                                                    \
    if (((D) & 3) == 0) pf.x = _pv;                                           \
    else if (((D) & 3) == 1) pf.y = _pv;                                      \
    else if (((D) & 3) == 2) pf.z = _pv;                                      \
    else {                                                                    \
        pf.w = _pv;                                                           \
        *(float4*)(wq + ((D) >> 2) * 256) = pf;                               \
    }                                                                         \
} while (0)

#pragma unroll
    for (int j = 0; j < CWT; ++j) {
        win[j & 31] = (double)sx[lane][CWT * w + 32 + j];   // push x[t]
        double a0 = 0.0, a1 = 0.0, a2 = 0.0;
#pragma unroll
        for (int i = 0; i < 8; ++i)  a0 = fma(w0d[i], win[(j + 25 + i) & 31], a0);
#pragma unroll
        for (int i = 0; i < 16; ++i) a1 = fma(w1d[i], win[(j + 17 + i) & 31], a1);
#pragma unroll
        for (int i = 0; i < 32; ++i) a2 = fma(w2d[i], win[(j + 1 + i) & 31], a2);
        a0 *= s8; a1 *= 0.25; a2 *= s32;

        const int t = t_start + j;
        float* wq = w32 + ((size_t)(t >> 4) * 4 + bgi) * 3072 + lane * 4;
        const int D0 = (j & 15) * 3;                        // t&15 == j&15
        PPUT((float)(a0 - 0.05), D0);
        PPUT((float)(a1 - 0.05), D0 + 1);
        PPUT((float)(a2 - 0.05), D0 + 2);

        fr0[j & 15] = (float)a0; fr1[j & 15] = (float)a1; fr2[j & 15] = (float)a2;
        if ((j & 15) == 15) {
            float* d = uf + t_start + (j & ~15);
#pragma unroll
            for (int q = 0; q < 4; ++q) {
                *(float4*)(d + 4 * q)         = ((float4*)fr0)[q];
                *(float4*)(d + T + 4 * q)     = ((float4*)fr1)[q];
                *(float4*)(d + 2 * T + 4 * q) = ((float4*)fr2)[q];
            }
        }
    }
#undef PPUT
}

// ---------------------------------------------------------------------------
// Scan: 4-wave shared-stream LIF-WTA. Block (bg,c): 48-group stream, one
// cooperative 12 KB group load per phase into a 6-slab LDS ring; wave w
// emits sub-chunk [c*256 + 64w, +64) behind a 512-step warm (exact for
// c<=1). Phase p: [own-vmcnt wait][bar][ds_read slab + 16 STEPs][bar]
// [issue 3 loads for G(p+6) into the just-freed slot][transposed emit].
// ---------------------------------------------------------------------------
__global__ __launch_bounds__(256, 1) void scan_kernel(
    const float* __restrict__ w32,
    float* __restrict__ s_out)        // [B][K][T] f32
{
    // XCD-aware remap: adjacent chunks (66% stream overlap) share an XCD L2.
    const int phys = blockIdx.x;
    const int xcd  = phys & 7;
    const int slot = phys >> 3;            // 32 blocks per XCD
    const int c    = 8 * xcd + (slot & 7); // contiguous chunk range per XCD
    const int bg   = slot >> 3;
    const int tid  = threadIdx.x;
    const int lane = tid & 63;
    const int w    = tid >> 6;             // wave id 0..3

    const int t_emit = c * CHUNK;
    const int t_w    = (t_emit >= WARM) ? (t_emit - WARM) : 0;
    const int tw16   = t_w >> 4;
    const int n_g    = (t_emit >> 4) + 16 - tw16;   // 16, 32, or 48 phases
    const int es     = n_g - 16 + 4 * w;            // emit-start phase (wave)
    const int as     = (es >= 32) ? (es - 32) : 0;  // active-start phase

    // 6-slab group ring (72 KB) + per-wave store-transpose stage (50 KB).
    __shared__ float4 ring[6 * 768];
    __shared__ float4 sstage[4][12 * 65];
    float4* ss = sstage[w];

    double m0 = -1.0, m1 = -1.0, m2 = -1.0;     // v=0 -> m=-1 exactly

#define WAITN(N) do {                                                   \
    asm volatile("s_waitcnt vmcnt(" #N ")" ::: "memory");               \
    __builtin_amdgcn_sched_barrier(0);                                  \
} while (0)

// Wave w DMAs rows 3w..3w+2 of group gg into ring slot sl (uniform LDS base;
// HW adds lane*16 -> linear slab image, same as proven R8/R10 staging).
#define ISSUE(sl, gg) do {                                                    \
    const float4* _src = (const float4*)(w32 +                                \
        ((size_t)(tw16 + (gg)) * 4 + bg) * 3072) + (size_t)(3 * w) * 64 + lane; \
    _Pragma("unroll")                                                         \
    for (int _q = 0; _q < 3; ++_q)                                            \
        __builtin_amdgcn_global_load_lds(                                     \
            (const __attribute__((address_space(1))) void*)(const void*)      \
                (_src + (size_t)_q * 64),                                     \
            (__attribute__((address_space(3))) void*)(void*)                  \
                (&ring[(sl) * 768 + (3 * w + _q) * 64]),                      \
            16, 0, 0);                                                        \
} while (0)

#define STEP(W0, W1, W2, O0, O1, O2) do {                               \
    const double M0 = fma(0.95, m0, (W0));                              \
    const double M1 = fma(0.95, m1, (W1));                              \
    const double M2 = fma(0.95, m2, (W2));                              \
    const bool c01 = (M0 >= M1);                                        \
    const bool c02 = (M0 >= M2);                                        \
    const bool c12 = (M1 >= M2);                                        \
    const bool f0  = (M0 >= 0.0);                                       \
    const bool f1  = (M1 >= 0.0);                                       \
    const bool f2  = (M2 >= 0.0);                                       \
    const bool s0 = c01 & c02 & f0;          /* first-index argmax */   \
    const bool s1 = (!c01) & c12 & f1;                                  \
    const bool s2 = (!c02) & (!c12) & f2;                               \
    m0 = s0 ? M0 - 1.0 : M0;                                            \
    m1 = s1 ? M1 - 1.0 : M1;                                            \
    m2 = s2 ? M2 - 1.0 : M2;                                            \
    (O0) = s0 ? 1.0f : 0.0f;                                            \
    (O1) = s1 ? 1.0f : 0.0f;                                            \
    (O2) = s2 ? 1.0f : 0.0f;                                            \
} while (0)

#define GETW(d) ( ((d) & 3) == 0 ? (double)_rf[(d) >> 2].x              \
                : ((d) & 3) == 1 ? (double)_rf[(d) >> 2].y              \
                : ((d) & 3) == 2 ? (double)_rf[(d) >> 2].z              \
                :                  (double)_rf[(d) >> 2].w )

    // Prologue: stage groups 0..5 (n_g >= 16 always).
#pragma unroll
    for (int g = 0; g < 6; ++g) ISSUE(g, g);

    for (int p = 0; p < 48; ++p) {
        if (p >= n_g) break;               // block-uniform

        // Wait for OWN 3 loads of group p (issued at phase p-6 / prologue).
        // Loads-only lower bound on newer ops (stores undercounted => safe
        // over-drain, confined to the last 5 phases): in-loop issues happen
        // while p_iss <= n_g-7, so newer = 3*min(5, n_g-1-p).
        {
            const int d = n_g - p;
            if (d >= 6)      WAITN(15);
            else if (d == 5) WAITN(12);
            else if (d == 4) WAITN(9);
            else if (d == 3) WAITN(6);
            else if (d == 2) WAITN(3);
            else             WAITN(0);
        }
        __syncthreads();                   // slab p complete for all waves

        const int sl = p % 6;
        const bool act = (p >= as) && (p < es + 4);
        float sp0[16], sp1[16], sp2[16];
        if (act) {
            const float4* _lp = ring + sl * 768 + lane;
            float4 _rf[12];
#pragma unroll
            for (int _q = 0; _q < 12; ++_q) _rf[_q] = _lp[(size_t)_q * 64];
#pragma unroll
            for (int _j = 0; _j < 16; ++_j) {
                const int _d0 = 3 * _j;
                STEP(GETW(_d0), GETW(_d0 + 1), GETW(_d0 + 2),
                     sp0[_j], sp1[_j], sp2[_j]);
            }
        }
        __syncthreads();                   // all reads of slot sl done (WAR)

        if (p + 6 < n_g) ISSUE(sl, p + 6); // re-target the just-freed slot

        if (act && p >= es) {
            // transpose via own LDS stage: full 64 B-line stores (R10-proven)
#pragma unroll
            for (int _q = 0; _q < 4; ++_q) {
                ss[(0 * 4 + _q) * 65 + lane] = ((float4*)sp0)[_q];
                ss[(1 * 4 + _q) * 65 + lane] = ((float4*)sp1)[_q];
                ss[(2 * 4 + _q) * 65 + lane] = ((float4*)sp2)[_q];
            }
            asm volatile("s_waitcnt lgkmcnt(0)" ::: "memory");
            __builtin_amdgcn_sched_barrier(0);
            const int _t = (tw16 + p) * 16;
#pragma unroll
            for (int _k = 0; _k < 3; ++_k) {
#pragma unroll
                for (int _g = 0; _g < 4; ++_g) {
                    const float4 _v =
                        ss[(_k * 4 + (lane & 3)) * 65 + _g * 16 + (lane >> 2)];
                    float* _dst = s_out
                        + (size_t)(bg * 64 + _g * 16 + (lane >> 2)) * (3 * T)
                        + (size_t)_k * T + _t + (lane & 3) * 4;
                    *(float4*)_dst = _v;
                }
            }
        }
    }

#undef GETW
#undef STEP
#undef ISSUE
#undef WAITN
}

// ---------------------------------------------------------------------------
extern "C" void kernel_launch(void* const* d_in, const int* in_sizes, int n_in,
                              void* d_out, int out_size, void* d_ws, size_t ws_size,
                              hipStream_t stream)
{
    const float* x  = (const float*)d_in[0];
    const float* w0 = (const float*)d_in[1];
    const float* w1 = (const float*)d_in[2];
    const float* w2 = (const float*)d_in[3];
    // d_in[4] = y (unused by the reference outputs)

    float* out   = (float*)d_out;
    float* u_out = out;                        // [B][K][T]
    float* s_out = out + (size_t)B * K * T;    // [B][K][T]

    float* w32 = (float*)d_ws;                 // 50.3 MB f32 panel (ws >= 100 MB)

    conv_kernel<<<(B / 64) * (T / CBT), 256, 0, stream>>>(x, w0, w1, w2, u_out, w32);
    scan_kernel<<<B, 256, 0, stream>>>(w32, s_out);
}